// Round 1
// baseline (7906.590 us; speedup 1.0000x reference)
//
#include <hip/hip_runtime.h>
#include <hip/hip_bf16.h>

// Problem constants
#define BATCH 32
#define CIN   256
#define COUT  256
#define FH    64
#define FW    64
#define NK    4          // experts
#define CTX   256
#define TEMP  30.0f

#define CI_CHUNK 64      // ci per weight-staging chunk

// ---------------- Kernel 1: attention = softmax((g @ dense_w + b)/T) -------
__global__ void attn_kernel(const float* __restrict__ g,
                            const float* __restrict__ dw,
                            const float* __restrict__ db,
                            float* __restrict__ att) {
    int tid = threadIdx.x;          // 128 threads: (b,k) = (tid>>2, tid&3)
    int b = tid >> 2;
    int k = tid & 3;
    float acc = db[k];
    const float* gp = g + b * CTX;
    for (int i = 0; i < CTX; ++i)
        acc += gp[i] * dw[i * NK + k];
    acc *= (1.0f / TEMP);
    // softmax over the 4 lanes of this quad (lanes are consecutive)
    float m = acc;
    m = fmaxf(m, __shfl_xor(m, 1));
    m = fmaxf(m, __shfl_xor(m, 2));
    float e = expf(acc - m);
    float s = e;
    s += __shfl_xor(s, 1);
    s += __shfl_xor(s, 2);
    att[b * NK + k] = e / s;
}

// ---------------- Kernel 2: per-sample 3x3 conv, direct, fp32 --------------
// Block: 256 threads. blockIdx.y = b, blockIdx.x = co-group (4 consecutive co).
// Each block covers the full 64x64 spatial plane; loops over ci, staging the
// 66x66 halo input plane in LDS and the 4x9 mixed weights per ci in registers.
// Each thread: 4x4 pixel tile x 4 co = 64 fp32 accumulators.
__global__ __launch_bounds__(256, 2) void conv_kernel(
        const float* __restrict__ x,
        const float* __restrict__ weight,
        const float* __restrict__ att,
        float* __restrict__ out) {
    __shared__ float wmix[CI_CHUNK * 4 * 12];   // [ci_local][co_j][12] (9 used)
    __shared__ float xin[66 * 68];              // rows 0..65 <-> iy -1..64, stride 68

    const int t   = threadIdx.x;
    const int b   = blockIdx.y;
    const int co0 = blockIdx.x * 4;

    const float a0 = att[b * 4 + 0];
    const float a1 = att[b * 4 + 1];
    const float a2 = att[b * 4 + 2];
    const float a3 = att[b * 4 + 3];

    float acc[4][4][4];
#pragma unroll
    for (int c = 0; c < 4; ++c)
#pragma unroll
        for (int i = 0; i < 4; ++i)
#pragma unroll
            for (int j = 0; j < 4; ++j)
                acc[c][i][j] = 0.0f;

    const int px = (t & 15) * 4;   // pixel-tile origin x
    const int py = (t >> 4) * 4;   // pixel-tile origin y
    const int tx = t & 63;         // staging col lane
    const int ty = t >> 6;         // staging row phase (0..3)

    const float* xb = x + (size_t)b * CIN * FH * FW;
    const size_t KSTRIDE = (size_t)COUT * CIN * 9;   // expert stride

    for (int ci0 = 0; ci0 < CIN; ci0 += CI_CHUNK) {
        __syncthreads();   // previous chunk's wmix reads done before overwrite
        {   // stage mixed weights for this chunk: thread -> (ci_l = t>>2, cj = t&3)
            int ci_l = t >> 2;
            int cj   = t & 3;
            const float* wp = weight + ((size_t)(co0 + cj) * CIN + (ci0 + ci_l)) * 9;
#pragma unroll
            for (int r = 0; r < 9; ++r) {
                float v = a0 * wp[r]
                        + a1 * wp[r + KSTRIDE]
                        + a2 * wp[r + 2 * KSTRIDE]
                        + a3 * wp[r + 3 * KSTRIDE];
                wmix[(ci_l * 4 + cj) * 12 + r] = v;
            }
        }
#pragma unroll 1
        for (int cil = 0; cil < CI_CHUNK; ++cil) {
            const int ci = ci0 + cil;
            __syncthreads();   // previous xin reads done; wmix writes visible
            // ---- stage input plane (b, ci) with halo + zero padding ----
            const float* xp = xb + (size_t)ci * FH * FW;
            for (int j = 0; j < 17; ++j) {
                int row = ty + 4 * j;           // 0..67
                if (row < 66) {
                    int iy = row - 1;           // -1..64
                    float v = 0.0f;
                    int ix = tx - 1;            // -1..62
                    if (iy >= 0 && iy < FH && ix >= 0)
                        v = xp[iy * FW + ix];
                    xin[row * 68 + tx] = v;
                    if (tx < 2) {               // cols 64,65 <-> ix 63,64
                        int ix2 = 63 + tx;
                        float v2 = 0.0f;
                        if (iy >= 0 && iy < FH && ix2 < FW)
                            v2 = xp[iy * FW + ix2];
                        xin[row * 68 + 64 + tx] = v2;
                    }
                }
            }
            __syncthreads();

            // ---- weights for this ci into registers (broadcast reads) ----
            float w[4][9];
#pragma unroll
            for (int c = 0; c < 4; ++c)
#pragma unroll
                for (int r = 0; r < 9; ++r)
                    w[c][r] = wmix[(cil * 4 + c) * 12 + r];

            // ---- compute: rolling 3-row register window, 6 cols each ----
            float rbuf[3][6];
#pragma unroll
            for (int rr = 0; rr < 2; ++rr)
#pragma unroll
                for (int j = 0; j < 6; ++j)
                    rbuf[rr][j] = xin[(py + rr) * 68 + px + j];

#pragma unroll
            for (int i = 0; i < 4; ++i) {
                // load row py+i+2 into slot (i+2)%3
#pragma unroll
                for (int j = 0; j < 6; ++j)
                    rbuf[(i + 2) % 3][j] = xin[(py + i + 2) * 68 + px + j];
                const float* q0 = rbuf[i % 3];
                const float* q1 = rbuf[(i + 1) % 3];
                const float* q2 = rbuf[(i + 2) % 3];
#pragma unroll
                for (int c = 0; c < 4; ++c) {
#pragma unroll
                    for (int j = 0; j < 4; ++j) {
                        float s = acc[c][i][j];
                        s = fmaf(w[c][0], q0[j],     s);
                        s = fmaf(w[c][1], q0[j + 1], s);
                        s = fmaf(w[c][2], q0[j + 2], s);
                        s = fmaf(w[c][3], q1[j],     s);
                        s = fmaf(w[c][4], q1[j + 1], s);
                        s = fmaf(w[c][5], q1[j + 2], s);
                        s = fmaf(w[c][6], q2[j],     s);
                        s = fmaf(w[c][7], q2[j + 1], s);
                        s = fmaf(w[c][8], q2[j + 2], s);
                        acc[c][i][j] = s;
                    }
                }
            }
        }
    }

    // ---- epilogue: coalesced float4 stores ----
#pragma unroll
    for (int c = 0; c < 4; ++c) {
#pragma unroll
        for (int i = 0; i < 4; ++i) {
            float* op = out + (((size_t)b * COUT + co0 + c) * FH + (py + i)) * FW + px;
            float4 v = make_float4(acc[c][i][0], acc[c][i][1], acc[c][i][2], acc[c][i][3]);
            *(float4*)op = v;
        }
    }
}

extern "C" void kernel_launch(void* const* d_in, const int* in_sizes, int n_in,
                              void* d_out, int out_size, void* d_ws, size_t ws_size,
                              hipStream_t stream) {
    const float* x       = (const float*)d_in[0];
    const float* g       = (const float*)d_in[1];
    const float* weight  = (const float*)d_in[2];
    const float* dense_w = (const float*)d_in[3];
    const float* dense_b = (const float*)d_in[4];
    float* out = (float*)d_out;
    float* att = (float*)d_ws;   // 32*4 floats

    attn_kernel<<<1, 128, 0, stream>>>(g, dense_w, dense_b, att);

    dim3 grid(COUT / 4, BATCH);   // 64 x 32 = 2048 blocks
    conv_kernel<<<grid, 256, 0, stream>>>(x, weight, att, out);
}

// Round 2
// 724.173 us; speedup vs baseline: 10.9181x; 10.9181x over previous
//
#include <hip/hip_runtime.h>
#include <hip/hip_bf16.h>
#include <stdint.h>

#define BATCH 32
#define CIN   256
#define COUT  256
#define FH    64
#define FW    64
#define NK    4
#define CTX   256
#define TEMP  30.0f

typedef __attribute__((ext_vector_type(8)))  short bf16x8;
typedef __attribute__((ext_vector_type(16))) float f32x16;

__device__ __forceinline__ unsigned short f2bf(float f) {
    union { float f; uint32_t u; } a; a.f = f;
    uint32_t r = a.u + 0x7fffu + ((a.u >> 16) & 1u);
    return (unsigned short)(r >> 16);
}

// ---------------- Kernel 1: attention = softmax((g @ dense_w + b)/T) -------
__global__ void attn_kernel(const float* __restrict__ g,
                            const float* __restrict__ dw,
                            const float* __restrict__ db,
                            float* __restrict__ att) {
    int tid = threadIdx.x;          // 128 threads: (b,k) = (tid>>2, tid&3)
    int b = tid >> 2;
    int k = tid & 3;
    float acc = db[k];
    const float* gp = g + b * CTX;
    for (int i = 0; i < CTX; ++i)
        acc += gp[i] * dw[i * NK + k];
    acc *= (1.0f / TEMP);
    float m = acc;
    m = fmaxf(m, __shfl_xor(m, 1));
    m = fmaxf(m, __shfl_xor(m, 2));
    float e = expf(acc - m);
    float s = e;
    s += __shfl_xor(s, 1);
    s += __shfl_xor(s, 2);
    att[b * NK + k] = e / s;
}

// ---------------- Kernel 2: expert mixing -> bf16 wmix in ws ---------------
// wmix layout: [b][tap][co][ci] bf16 (element idx ((b*9+tap)*256+co)*256+ci)
// chosen so conv's A-tiles are contiguous for global_load_lds width-16.
__global__ void mix_kernel(const float* __restrict__ weight,
                           const float* __restrict__ att,
                           unsigned short* __restrict__ wmix) {
    int ci = threadIdx.x;      // 0..255
    int co = blockIdx.x;       // 0..255
    int b  = blockIdx.y;       // 0..31
    float a0 = att[b * 4 + 0], a1 = att[b * 4 + 1];
    float a2 = att[b * 4 + 2], a3 = att[b * 4 + 3];
    const size_t EST = (size_t)COUT * CIN * 9;        // expert stride
    const float* wp = weight + ((size_t)co * CIN + ci) * 9;
#pragma unroll
    for (int r = 0; r < 9; ++r) {
        float v = a0 * wp[r] + a1 * wp[r + EST] + a2 * wp[r + 2 * EST] + a3 * wp[r + 3 * EST];
        wmix[((size_t)(b * 9 + r) * COUT + co) * CIN + ci] = f2bf(v);
    }
}

// ---------------- Kernel 3: implicit-GEMM conv via bf16 MFMA ---------------
// Block: 256 thr (4 waves). Tile: 128 co x 128 px (2 image rows) of batch b.
// Wave (wm,wn): 64co x 64px = 2x2 of mfma_f32_32x32x16_bf16.
// K-loop: 16 ci-chunks x 9 taps. A staged via global_load_lds (16B);
// B = 4row x 66col x 16ci halo patch, ci padded to 24 bf16 (48B) for
// alignment + conflict-free b128 frag reads.
__global__ __launch_bounds__(256, 3) void conv_mfma(
        const float* __restrict__ x,
        const unsigned short* __restrict__ wmix,
        float* __restrict__ out) {
    __shared__ __align__(16) short As[9 * 2048];      // [tap][h][co128][8ci] = 36864 B
    __shared__ __align__(16) char  Bs[4 * 66 * 48];   // [row][col][24 bf16]  = 12672 B

    const int tid  = threadIdx.x;
    const int lane = tid & 63;
    const int wv   = tid >> 6;
    const int wm   = wv & 1;          // co half (64)
    const int wn   = wv >> 1;         // px half (64) == image row within tile
    const int nn   = lane & 31;
    const int hh   = lane >> 5;       // k-half for MFMA frags

    const int ptile = blockIdx.x;     // 0..31 -> rows y0, y0+1
    const int coT   = blockIdx.y;     // 0..1
    const int b     = blockIdx.z;     // 0..31
    const int y0    = ptile * 2;

    const char*  wmix_b = (const char*)wmix + (size_t)b * 9 * 65536 * 2;
    const float* xb     = x + (size_t)b * CIN * (FH * FW);

    f32x16 acc[2][2];
#pragma unroll
    for (int i = 0; i < 2; ++i)
#pragma unroll
        for (int j = 0; j < 2; ++j)
#pragma unroll
            for (int r = 0; r < 16; ++r)
                acc[i][j][r] = 0.0f;

#pragma unroll 1
    for (int chunk = 0; chunk < 16; ++chunk) {
        const int ci0 = chunk * 16;
        __syncthreads();   // previous iteration's LDS reads complete

        // ---- A staging: 36 segments of 1KB via global_load_lds(16B) ----
        for (int s = wv; s < 36; s += 4) {
            const int tap = s >> 2, q = s & 3, h = q >> 1, ch = q & 1;
            const char* g = wmix_b + (size_t)tap * 131072
                          + (size_t)(coT * 128 + ch * 64 + lane) * 512
                          + (size_t)ci0 * 2 + h * 16;
            char* l = (char*)As + tap * 4096 + h * 2048 + ch * 1024;
            __builtin_amdgcn_global_load_lds(
                (const __attribute__((address_space(1))) void*)g,
                (__attribute__((address_space(3))) void*)l, 16, 0, 0);
        }

        // ---- B staging: wave wv stages patch row wv (iy = y0 + wv - 1) ----
        {
            const int iy    = y0 + wv - 1;
            const bool rowok = (iy >= 0) && (iy < FH);
            const int col   = lane;          // 0..63 ; cols 64,65 by lanes 0,1
            const int ix    = col - 1;
            const float* xrow = xb + (size_t)ci0 * (FH * FW) + (size_t)iy * FW;
            char* brow = Bs + (wv * 66 + col) * 48;
#pragma unroll
            for (int p = 0; p < 8; ++p) {
                const float* xp0 = xrow + (size_t)(2 * p) * (FH * FW);
                float v0 = (rowok && ix >= 0) ? xp0[ix] : 0.0f;
                float v1 = (rowok && ix >= 0) ? xp0[FH * FW + ix] : 0.0f;
                *(uint32_t*)(brow + p * 4) =
                    (uint32_t)f2bf(v0) | ((uint32_t)f2bf(v1) << 16);
                if (col < 2) {               // cols 64,65 <-> ix 63,64
                    const int ix2 = 63 + col;
                    float w0 = (rowok && ix2 < FW) ? xp0[ix2] : 0.0f;
                    float w1 = (rowok && ix2 < FW) ? xp0[FH * FW + ix2] : 0.0f;
                    *(uint32_t*)(Bs + (wv * 66 + 64 + col) * 48 + p * 4) =
                        (uint32_t)f2bf(w0) | ((uint32_t)f2bf(w1) << 16);
                }
            }
        }
        __syncthreads();   // staging visible (drains vmcnt for global_load_lds)

        // ---- 9 tap-steps: 4 b128 frag loads + 4 MFMAs each ----
#pragma unroll
        for (int tap = 0; tap < 9; ++tap) {
            const int dy = tap / 3, dx = tap % 3;
            const char* abase = (const char*)As + tap * 4096 + hh * 2048;
            bf16x8 a0 = *(const bf16x8*)(abase + (wm * 64 + nn) * 16);
            bf16x8 a1 = *(const bf16x8*)(abase + (wm * 64 + 32 + nn) * 16);
            const char* bbase = Bs + hh * 16;
            bf16x8 b0 = *(const bf16x8*)(bbase + (((wn + dy) * 66) + nn + dx) * 48);
            bf16x8 b1 = *(const bf16x8*)(bbase + (((wn + dy) * 66) + 32 + nn + dx) * 48);
            acc[0][0] = __builtin_amdgcn_mfma_f32_32x32x16_bf16(a0, b0, acc[0][0], 0, 0, 0);
            acc[0][1] = __builtin_amdgcn_mfma_f32_32x32x16_bf16(a0, b1, acc[0][1], 0, 0, 0);
            acc[1][0] = __builtin_amdgcn_mfma_f32_32x32x16_bf16(a1, b0, acc[1][0], 0, 0, 0);
            acc[1][1] = __builtin_amdgcn_mfma_f32_32x32x16_bf16(a1, b1, acc[1][1], 0, 0, 0);
        }
    }

    // ---- epilogue: C/D layout col=lane&31, row=(r&3)+8*(r>>2)+4*(lane>>5) ----
    const int y = y0 + wn;
#pragma unroll
    for (int sm = 0; sm < 2; ++sm)
#pragma unroll
        for (int sn = 0; sn < 2; ++sn)
#pragma unroll
            for (int r = 0; r < 16; ++r) {
                const int co = coT * 128 + wm * 64 + sm * 32 + ((r & 3) + 8 * (r >> 2) + 4 * hh);
                const int xx = sn * 32 + nn;
                out[(((size_t)b * COUT + co) * FH + y) * FW + xx] = acc[sm][sn][r];
            }
}

extern "C" void kernel_launch(void* const* d_in, const int* in_sizes, int n_in,
                              void* d_out, int out_size, void* d_ws, size_t ws_size,
                              hipStream_t stream) {
    const float* x       = (const float*)d_in[0];
    const float* g       = (const float*)d_in[1];
    const float* weight  = (const float*)d_in[2];
    const float* dense_w = (const float*)d_in[3];
    const float* dense_b = (const float*)d_in[4];
    float* out = (float*)d_out;

    float*          att  = (float*)d_ws;                              // 128 floats
    unsigned short* wmix = (unsigned short*)((char*)d_ws + 1024);     // 37.75 MB bf16

    attn_kernel<<<1, 128, 0, stream>>>(g, dense_w, dense_b, att);
    mix_kernel<<<dim3(COUT, BATCH), CIN, 0, stream>>>(weight, att, wmix);

    dim3 grid(32, 2, BATCH);   // px-tiles x co-tiles x batch = 2048 blocks
    conv_mfma<<<grid, 256, 0, stream>>>(x, wmix, out);
}

// Round 3
// 659.961 us; speedup vs baseline: 11.9804x; 1.0973x over previous
//
#include <hip/hip_runtime.h>
#include <hip/hip_bf16.h>
#include <stdint.h>

#define BATCH 32
#define CIN   256
#define COUT  256
#define FH    64
#define FW    64
#define NK    4
#define CTX   256
#define TEMP  30.0f

typedef __attribute__((ext_vector_type(8))) short bf16x8;
typedef __attribute__((ext_vector_type(4))) float f32x4;

__device__ __forceinline__ unsigned short f2bf(float f) {
    union { float f; uint32_t u; } a; a.f = f;
    uint32_t r = a.u + 0x7fffu + ((a.u >> 16) & 1u);
    return (unsigned short)(r >> 16);
}

// ws layout
#define WMIX_OFF  1024
#define WMIX_BYTES (32u * 9u * 8u * 4u * 256u * 16u)        // 37,748,736
#define XP_OFF    (WMIX_OFF + WMIX_BYTES)
// xp: [b][ch8][q4][y66][col68][r8] bf16  -> 32*8*4*66*68*16 B = 73,383,936

// ---------------- Kernel 1: attention ---------------------------------------
__global__ void attn_kernel(const float* __restrict__ g,
                            const float* __restrict__ dw,
                            const float* __restrict__ db,
                            float* __restrict__ att) {
    int tid = threadIdx.x;          // 128 threads: (b,k) = (tid>>2, tid&3)
    int b = tid >> 2;
    int k = tid & 3;
    float acc = db[k];
    const float* gp = g + b * CTX;
    for (int i = 0; i < CTX; ++i)
        acc += gp[i] * dw[i * NK + k];
    acc *= (1.0f / TEMP);
    float m = acc;
    m = fmaxf(m, __shfl_xor(m, 1));
    m = fmaxf(m, __shfl_xor(m, 2));
    float e = expf(acc - m);
    float s = e;
    s += __shfl_xor(s, 1);
    s += __shfl_xor(s, 2);
    att[b * NK + k] = e / s;
}

// ---------------- Kernel 2: expert mix -> wmix [b][tap][ch][q][co][r8] ------
__global__ void mix_kernel(const float* __restrict__ weight,
                           const float* __restrict__ att,
                           uint32_t* __restrict__ wmix) {
    const int co  = threadIdx.x;    // 0..255
    const int tap = blockIdx.x;     // 0..8
    const int b   = blockIdx.y;     // 0..31
    const float a0 = att[b * 4 + 0], a1 = att[b * 4 + 1];
    const float a2 = att[b * 4 + 2], a3 = att[b * 4 + 3];
    const size_t EST = (size_t)COUT * CIN * 9;
    const float* wp = weight + (size_t)co * CIN * 9 + tap;
    for (int ch = 0; ch < 8; ++ch) {
        for (int q = 0; q < 4; ++q) {
            uint32_t d[4];
#pragma unroll
            for (int rp = 0; rp < 4; ++rp) {
                uint32_t lohi = 0;
#pragma unroll
                for (int h = 0; h < 2; ++h) {
                    int ci = ch * 32 + q * 8 + rp * 2 + h;
                    const float* w0 = wp + (size_t)ci * 9;
                    float v = a0 * w0[0] + a1 * w0[EST] + a2 * w0[2 * EST] + a3 * w0[3 * EST];
                    lohi |= ((uint32_t)f2bf(v)) << (16 * h);
                }
                d[rp] = lohi;
            }
            // 16B coalesced store: dword idx = (((b*9+tap)*8+ch)*4+q)*256*4 + co*4
            uint32_t* dst = wmix + ((((size_t)(b * 9 + tap) * 8 + ch) * 4 + q) * 256 + co) * 4;
            *(uint4*)dst = make_uint4(d[0], d[1], d[2], d[3]);
        }
    }
}

// ---------------- Kernel 3: x -> bf16 halo-padded xp ------------------------
// xp[b][ch][q][y66][col68][r8]; y=0/65 zero rows, col 0,65,66,67 zero.
__global__ void xpad_kernel(const float* __restrict__ x,
                            uint32_t* __restrict__ xp) {
    __shared__ uint32_t P[1088];    // [q4][col68][rpair4] dwords = 4352 B
    const int t  = threadIdx.x;
    const int y  = blockIdx.x;      // 0..65
    const int ch = blockIdx.y;      // 0..7
    const int b  = blockIdx.z;      // 0..31

    // zero LDS
    for (int i = t; i < 1088; i += 256) P[i] = 0;
    __syncthreads();

    if (y >= 1 && y <= 64) {
        const int ci_l = t >> 3;            // 0..31
        const int col0 = (t & 7) * 8;       // 0..56
        const float* xr = x + (((size_t)(b * 256 + ch * 32 + ci_l) * 64) + (y - 1)) * 64 + col0;
        float4 v0 = *(const float4*)xr;
        float4 v1 = *(const float4*)(xr + 4);
        unsigned short bf[8];
        bf[0] = f2bf(v0.x); bf[1] = f2bf(v0.y); bf[2] = f2bf(v0.z); bf[3] = f2bf(v0.w);
        bf[4] = f2bf(v1.x); bf[5] = f2bf(v1.y); bf[6] = f2bf(v1.z); bf[7] = f2bf(v1.w);
        const int q = ci_l >> 3, r = ci_l & 7;
        unsigned short* Ps = (unsigned short*)P;
#pragma unroll
        for (int j = 0; j < 8; ++j)
            Ps[(q * 68 + (col0 + j + 1)) * 8 + r] = bf[j];
    }
    __syncthreads();

    // write out: per q plane, 272 dwords, planes 71808 B apart
    const int q = t >> 6, l = t & 63;
    uint32_t* base = xp + (((((size_t)(b * 8 + ch) * 4 + q) * 66) + y) * 68) * 4;  // dwords
#pragma unroll
    for (int i = 0; i < 4; ++i)
        base[l + i * 64] = P[q * 272 + l + i * 64];
    if (l < 16) base[l + 256] = P[q * 272 + l + 256];
}

// ---------------- Kernel 4: implicit-GEMM conv, m97-style -------------------
// Block 256 thr (4 waves, 2co x 2px). Tile 128co x 128px (rows y0,y0+1).
// Wave: 64co x 64px = 4x4 of mfma_f32_16x16x32_bf16.
// Phase = (ci-chunk of 32) x (dy group of 3 taps): stage A3 24.6KB + B2 8.7KB
// entirely via global_load_lds(16B), then 3 dx K-steps of 16 MFMAs.
__global__ __launch_bounds__(256, 3) void conv_mfma(
        const char* __restrict__ xp,
        const char* __restrict__ wmix,
        float* __restrict__ out) {
    __shared__ __align__(16) short As[3 * 4 * 128 * 8];   // 24576 B [dx][q][co128][r8]
    __shared__ __align__(16) short Bs[4 * 2 * 68 * 8];    //  8704 B [q][row2][col68][r8]

    const int tid  = threadIdx.x;
    const int lane = tid & 63;
    const int wv   = tid >> 6;
    const int wm   = wv & 1;          // co half
    const int wn   = wv >> 1;         // px half == image row offset
    const int l4   = lane >> 4;       // k-quad
    const int m16  = lane & 15;

    const int ptile = blockIdx.x;     // 0..31
    const int coT   = blockIdx.y;     // 0..1
    const int b     = blockIdx.z;     // 0..31
    const int y0    = ptile * 2;

    const char* wmix_b = wmix + (size_t)b * 9 * 8 * 4 * 256 * 16;
    const char* xp_b   = xp + (size_t)b * 8 * 4 * 66 * 68 * 16;

    f32x4 acc[4][4];
#pragma unroll
    for (int i = 0; i < 4; ++i)
#pragma unroll
        for (int j = 0; j < 4; ++j)
            acc[i][j] = (f32x4){0.f, 0.f, 0.f, 0.f};

    const int aLane = l4 * 2048 + wm * 1024 + m16 * 16;   // byte off in As
    const int bLane = l4 * 2176 + wn * 1088 + m16 * 16;   // byte off in Bs

#pragma unroll 1
    for (int ch = 0; ch < 8; ++ch) {
#pragma unroll 1
        for (int dy = 0; dy < 3; ++dy) {
            __syncthreads();   // previous phase reads done
            // ---- A staging: 24 segments of 1KB (6 per wave) ----
#pragma unroll
            for (int i = 0; i < 6; ++i) {
                const int s  = wv + i * 4;      // 0..23
                const int dx = s >> 3;
                const int q  = (s >> 1) & 3;
                const int h  = s & 1;
                const char* gsrc = wmix_b
                    + ((size_t)((dy * 3 + dx) * 8 + ch) * 4 + q) * 4096
                    + (coT * 128 + h * 64 + lane) * 16;
                char* ldst = (char*)As + ((dx * 4 + q) * 128 + h * 64 + lane) * 16;
                __builtin_amdgcn_global_load_lds(
                    (const __attribute__((address_space(1))) void*)gsrc,
                    (__attribute__((address_space(3))) void*)ldst, 16, 0, 0);
            }
            // ---- B staging: wave wv stages q=wv, rows yb..yb+1 (2176 B) ----
            {
                const int yb = y0 + dy;     // padded-row index, 0..64
                const char* gsrc = xp_b
                    + (((size_t)ch * 4 + wv) * 66 + yb) * 1088 + lane * 16;
                char* ldst = (char*)Bs + wv * 2176 + lane * 16;
                __builtin_amdgcn_global_load_lds(
                    (const __attribute__((address_space(1))) void*)gsrc,
                    (__attribute__((address_space(3))) void*)ldst, 16, 0, 0);
                __builtin_amdgcn_global_load_lds(
                    (const __attribute__((address_space(1))) void*)(gsrc + 1024),
                    (__attribute__((address_space(3))) void*)(ldst + 1024), 16, 0, 0);
                if (lane < 8)
                    __builtin_amdgcn_global_load_lds(
                        (const __attribute__((address_space(1))) void*)(gsrc + 2048),
                        (__attribute__((address_space(3))) void*)(ldst + 2048), 16, 0, 0);
            }
            __syncthreads();   // staging visible

            // ---- compute: 3 dx K-steps x 16 MFMAs ----
#pragma unroll
            for (int dx = 0; dx < 3; ++dx) {
                bf16x8 a[4], bb[4];
#pragma unroll
                for (int sm = 0; sm < 4; ++sm)
                    a[sm] = *(const bf16x8*)((const char*)As + dx * 8192 + aLane + sm * 256);
#pragma unroll
                for (int sn = 0; sn < 4; ++sn)
                    bb[sn] = *(const bf16x8*)((const char*)Bs + bLane + dx * 16 + sn * 256);
#pragma unroll
                for (int sm = 0; sm < 4; ++sm)
#pragma unroll
                    for (int sn = 0; sn < 4; ++sn)
                        acc[sm][sn] = __builtin_amdgcn_mfma_f32_16x16x32_bf16(
                            a[sm], bb[sn], acc[sm][sn], 0, 0, 0);
            }
        }
    }

    // ---- epilogue: D col=lane&15 (px), row=(lane>>4)*4+reg (co) ----
    const int y = y0 + wn;
#pragma unroll
    for (int sm = 0; sm < 4; ++sm) {
#pragma unroll
        for (int sn = 0; sn < 4; ++sn) {
#pragma unroll
            for (int r = 0; r < 4; ++r) {
                const int co = coT * 128 + wm * 64 + sm * 16 + l4 * 4 + r;
                const int xx = sn * 16 + m16;
                out[(((size_t)b * COUT + co) * FH + y) * FW + xx] = acc[sm][sn][r];
            }
        }
    }
}

extern "C" void kernel_launch(void* const* d_in, const int* in_sizes, int n_in,
                              void* d_out, int out_size, void* d_ws, size_t ws_size,
                              hipStream_t stream) {
    const float* x       = (const float*)d_in[0];
    const float* g       = (const float*)d_in[1];
    const float* weight  = (const float*)d_in[2];
    const float* dense_w = (const float*)d_in[3];
    const float* dense_b = (const float*)d_in[4];
    float* out = (float*)d_out;

    float*    att  = (float*)d_ws;
    uint32_t* wmix = (uint32_t*)((char*)d_ws + WMIX_OFF);
    uint32_t* xp   = (uint32_t*)((char*)d_ws + XP_OFF);

    attn_kernel<<<1, 128, 0, stream>>>(g, dense_w, dense_b, att);
    mix_kernel<<<dim3(9, BATCH), 256, 0, stream>>>(weight, att, wmix);
    xpad_kernel<<<dim3(66, 8, BATCH), 256, 0, stream>>>(x, xp);

    dim3 grid(32, 2, BATCH);
    conv_mfma<<<grid, 256, 0, stream>>>((const char*)xp, (const char*)wmix, out);
}